// Round 4
// baseline (72.709 us; speedup 1.0000x reference)
//
#include <hip/hip_runtime.h>
#include <cmath>
#include <cstdint>

#define LLEN 131072
#define IIRL 16384
#define CHUNK 4096
#define NBLK (LLEN / CHUNK)   // 32 chunks per row
#define TPB 256
#define EPT (CHUNK / TPB)     // 16 elements per thread

__device__ __forceinline__ float powiu(float b, unsigned e) {
    float r = 1.0f;
    while (e) { if (e & 1u) r *= b; b *= b; e >>= 1; }
    return r;
}

__device__ __forceinline__ float sigmoidf(float z) {
    return 1.0f / (1.0f + expf(-z));
}

// ---------------------------------------------------------------------------
// Fused single-pass compressor with decoupled lookback (no grid sync):
//   phase A: per-chunk partial env (zero carry-in), publish as {ready|bits}
//            via device-scope release store.
//   phase B: wave 0 spin-loads the <=31 predecessor partials (one per lane,
//            acquire), shuffle-reduces the weighted carry; then env scan,
//            quadratic-knee gain, write. Input is read exactly once.
// env[t] = a*env[t-1] + (1-a)*(ls[t] - A16K*ls[t-16384]),  ls = mean_c(x^2)
// Deadlock-free: blocks wait only on earlier blockIdx.x of the same row, and
// the 1024-block grid is fully co-resident at 4 blocks/CU regardless.
// ---------------------------------------------------------------------------
__global__ __launch_bounds__(TPB, 4) void k_fused(
    const float* __restrict__ x, const float* __restrict__ za,
    const float* __restrict__ lt, const float* __restrict__ lr,
    const float* __restrict__ lk, uint64_t* __restrict__ P,
    float* __restrict__ out)
{
    const int chunk = blockIdx.x, n = blockIdx.y;
    const int tid = threadIdx.x, lane = tid & 63, wid = tid >> 6;

    const float alpha = sigmoidf(za[n]);
    const float oma   = 1.0f - alpha;
    const float A16K  = powiu(alpha, IIRL);   // 0 for realistic alpha
    const float Tthr  = lt[n] - 6.0f;
    const float ratio = 1.0f + expf(lr[n]);
    const float knee  = expf(lk[n] - 1.0f);
    const float coef  = (1.0f / ratio - 1.0f) / knee;

    const long  base = (long)n * 2 * LLEN + (long)chunk * CHUNK;
    const float* x0 = x + base;
    const float* x1 = x0 + LLEN;
    const int j0 = tid * EPT;

    // ---- load input once, keep in registers; b = oma * mean_c(x^2) ----
    float4 xa[4], xb[4];
    float  b[EPT];
    {
        const float4* p0 = reinterpret_cast<const float4*>(x0 + j0);
        const float4* p1 = reinterpret_cast<const float4*>(x1 + j0);
        #pragma unroll
        for (int q = 0; q < 4; ++q) {
            xa[q] = p0[q]; xb[q] = p1[q];
            float4 a = xa[q], c = xb[q];
            b[q*4+0] = oma * 0.5f * fmaf(a.x, a.x, c.x*c.x);
            b[q*4+1] = oma * 0.5f * fmaf(a.y, a.y, c.y*c.y);
            b[q*4+2] = oma * 0.5f * fmaf(a.z, a.z, c.z*c.z);
            b[q*4+3] = oma * 0.5f * fmaf(a.w, a.w, c.w*c.w);
        }
    }
    if (A16K != 0.0f && chunk >= IIRL / CHUNK) {   // uniform per-block branch
        const float4* p0 = reinterpret_cast<const float4*>(x0 + j0 - IIRL);
        const float4* p1 = reinterpret_cast<const float4*>(x1 + j0 - IIRL);
        const float sc = oma * A16K * 0.5f;
        #pragma unroll
        for (int q = 0; q < 4; ++q) {
            float4 a = p0[q], c = p1[q];
            b[q*4+0] -= sc * fmaf(a.x, a.x, c.x*c.x);
            b[q*4+1] -= sc * fmaf(a.y, a.y, c.y*c.y);
            b[q*4+2] -= sc * fmaf(a.z, a.z, c.z*c.z);
            b[q*4+3] -= sc * fmaf(a.w, a.w, c.w*c.w);
        }
    }

    // ---- phase A: thread scan -> wave scan -> block partial ----
    float s = 0.0f;
    #pragma unroll
    for (int i = 0; i < EPT; ++i) s = fmaf(alpha, s, b[i]);

    const float a16 = powiu(alpha, 16u);
    float v = s, g = a16;
    #pragma unroll
    for (int off = 1; off < 64; off <<= 1) {
        float y = __shfl_up(v, off, 64);
        if (lane >= off) v = fmaf(g, y, v);
        g *= g;
    }
    float Ew = __shfl_up(v, 1, 64);   // exclusive within-wave
    if (lane == 0) Ew = 0.0f;

    __shared__ float wtot[TPB / 64];
    __shared__ float carry_s;
    if (lane == 63) wtot[wid] = v;
    __syncthreads();

    const float A1024 = powiu(a16, 64u);   // alpha^1024 (per-wave span)
    if (tid == 0) {
        float p = 0.0f;
        #pragma unroll
        for (int w = 0; w < TPB / 64; ++w) p = fmaf(A1024, p, wtot[w]);
        const uint64_t pk = (1ull << 32) | (uint64_t)__float_as_uint(p);
        __hip_atomic_store(&P[n * NBLK + chunk], pk,
                           __ATOMIC_RELEASE, __HIP_MEMORY_SCOPE_AGENT);
    }
    float wc = 0.0f;                       // exclusive over preceding waves
    for (int w = 0; w < wid; ++w) wc = fmaf(A1024, wc, wtot[w]);
    const float a16l = powiu(a16, (unsigned)lane);   // alpha^(16*lane)
    const float pre_blk = fmaf(a16l, wc, Ew);        // block-local exclusive

    // ---- phase B: parallel spin-lookback over predecessor chunks ----
    if (chunk == 0) {
        if (tid == 0) carry_s = 0.0f;
    } else if (wid == 0) {
        float cv = 0.0f;
        if (lane < chunk) {
            const float Ac = powiu(alpha, (unsigned)CHUNK);
            uint64_t e;
            for (;;) {
                e = __hip_atomic_load(&P[n * NBLK + lane],
                                      __ATOMIC_ACQUIRE, __HIP_MEMORY_SCOPE_AGENT);
                if (e >> 32) break;
                __builtin_amdgcn_s_sleep(1);
            }
            cv = powiu(Ac, (unsigned)(chunk - 1 - lane)) *
                 __uint_as_float((uint32_t)(e & 0xffffffffu));
        }
        #pragma unroll
        for (int off = 32; off; off >>= 1) cv += __shfl_xor(cv, off, 64);
        if (lane == 0) carry_s = cv;
    }
    __syncthreads();
    const float carry = carry_s;

    // env value just before this thread's first element
    float e = fmaf(a16l * powiu(A1024, (unsigned)wid), carry, pre_blk);

    // ---- element-wise env + gain + output ----
    #pragma unroll
    for (int q = 0; q < 4; ++q) {
        float4 oa, ob;
        float* poa = reinterpret_cast<float*>(&oa);
        float* pob = reinterpret_cast<float*>(&ob);
        const float* ia = reinterpret_cast<const float*>(&xa[q]);
        const float* ib = reinterpret_cast<const float*>(&xb[q]);
        #pragma unroll
        for (int k = 0; k < 4; ++k) {
            e = fmaf(alpha, e, b[q*4 + k]);
            float le = logf(e + 1e-5f);
            float xk = knee * (le - Tthr);
            float sp = fmaxf(xk, 0.0f) + log1pf(expf(-fabsf(xk)));
            float gain = expf(coef * sp);
            poa[k] = gain * ia[k];
            pob[k] = gain * ib[k];
        }
        reinterpret_cast<float4*>(out + base + j0)[q]        = oa;
        reinterpret_cast<float4*>(out + base + LLEN + j0)[q] = ob;
    }
}

extern "C" void kernel_launch(void* const* d_in, const int* in_sizes, int n_in,
                              void* d_out, int out_size, void* d_ws, size_t ws_size,
                              hipStream_t stream) {
    const float* x  = (const float*)d_in[0];
    const float* za = (const float*)d_in[1];
    const float* lt = (const float*)d_in[2];
    const float* lr = (const float*)d_in[3];
    const float* lk = (const float*)d_in[4];
    float* out = (float*)d_out;
    uint64_t* P = (uint64_t*)d_ws;         // N*NBLK packed {ready|float} = 8 KB

    const int N = in_sizes[1];             // z_alpha is (N,1)
    // clear ready bits every call (d_ws is NOT re-poisoned between replays)
    hipMemsetAsync(P, 0, (size_t)N * NBLK * sizeof(uint64_t), stream);
    dim3 grid(NBLK, N), block(TPB);
    k_fused<<<grid, block, 0, stream>>>(x, za, lt, lr, lk, P, out);
}

// Round 5
// 35.525 us; speedup vs baseline: 2.0467x; 2.0467x over previous
//
#include <hip/hip_runtime.h>
#include <cmath>

#define LLEN 131072
#define IIRL 16384
#define CHUNK 16384           // == IIRL: dependency window = exactly 1 chunk
#define NBLK (LLEN / CHUNK)   // 8 chunks per row
#define TPB 1024
#define EPT (CHUNK / TPB)     // 16 elements per thread
#define NW (TPB / 64)         // 16 waves

__device__ __forceinline__ float powiu(float b, unsigned e) {
    float r = 1.0f;
    while (e) { if (e & 1u) r *= b; b *= b; e >>= 1; }
    return r;
}

__device__ __forceinline__ float sigmoidf(float z) {
    return 1.0f / (1.0f + expf(-z));
}

// ---------------------------------------------------------------------------
// Fully independent blocks: CHUNK == IIRL, so env[t] for t in this chunk
// depends only on {prev chunk, own chunk}. Each block:
//   1. weighted-scan of prev chunk -> exact carry env[start-1] (any alpha)
//   2. scan own chunk with carry, tail-corrected recurrence
//   3. quadratic-knee gain, write both channels
// env[t] = a*env[t-1] + (1-a)*(ls[t] - a^16384 * ls[t-16384]), ls = mean_c(x^2)
// ---------------------------------------------------------------------------
__global__ __launch_bounds__(TPB) void k_fused(
    const float* __restrict__ x, const float* __restrict__ za,
    const float* __restrict__ lt, const float* __restrict__ lr,
    const float* __restrict__ lk, float* __restrict__ out)
{
    const int chunk = blockIdx.x, n = blockIdx.y;
    const int tid = threadIdx.x, lane = tid & 63, wid = tid >> 6;

    const float alpha = sigmoidf(za[n]);
    const float oma   = 1.0f - alpha;
    const float A16K  = powiu(alpha, IIRL);   // ~always 0 in fp32
    const float Tthr  = lt[n] - 6.0f;
    const float ratio = 1.0f + expf(lr[n]);
    const float knee  = expf(lk[n] - 1.0f);
    const float coef  = (1.0f / ratio - 1.0f) / knee;

    const long  base = (long)n * 2 * LLEN + (long)chunk * CHUNK;
    const float* x0 = x + base;
    const float* x1 = x0 + LLEN;
    const int j0 = tid * EPT;

    const float a16   = powiu(alpha, 16u);     // per-thread segment weight
    const float A1024 = powiu(a16, 64u);       // per-wave segment weight

    __shared__ float wtotA[NW];   // prev-chunk wave totals
    __shared__ float wtotB[NW];   // own-chunk wave totals

    // ---- 1. prev-chunk weighted total (exact carry, window == prev chunk) ----
    float s_prev = 0.0f;
    if (chunk > 0) {
        const float4* p0 = reinterpret_cast<const float4*>(x0 - CHUNK + j0);
        const float4* p1 = reinterpret_cast<const float4*>(x1 - CHUNK + j0);
        #pragma unroll
        for (int q = 0; q < 4; ++q) {
            float4 a = p0[q], c = p1[q];
            float l0 = oma * 0.5f * fmaf(a.x, a.x, c.x*c.x);
            float l1 = oma * 0.5f * fmaf(a.y, a.y, c.y*c.y);
            float l2 = oma * 0.5f * fmaf(a.z, a.z, c.z*c.z);
            float l3 = oma * 0.5f * fmaf(a.w, a.w, c.w*c.w);
            s_prev = fmaf(alpha, s_prev, l0);
            s_prev = fmaf(alpha, s_prev, l1);
            s_prev = fmaf(alpha, s_prev, l2);
            s_prev = fmaf(alpha, s_prev, l3);
        }
    }

    // ---- own chunk: load once, keep in registers ----
    float4 xa[4], xb[4];
    float  b[EPT];
    {
        const float4* p0 = reinterpret_cast<const float4*>(x0 + j0);
        const float4* p1 = reinterpret_cast<const float4*>(x1 + j0);
        #pragma unroll
        for (int q = 0; q < 4; ++q) {
            xa[q] = p0[q]; xb[q] = p1[q];
            float4 a = xa[q], c = xb[q];
            b[q*4+0] = oma * 0.5f * fmaf(a.x, a.x, c.x*c.x);
            b[q*4+1] = oma * 0.5f * fmaf(a.y, a.y, c.y*c.y);
            b[q*4+2] = oma * 0.5f * fmaf(a.z, a.z, c.z*c.z);
            b[q*4+3] = oma * 0.5f * fmaf(a.w, a.w, c.w*c.w);
        }
    }
    if (A16K != 0.0f && chunk > 0) {   // pathological alpha: exact tail term
        const float4* p0 = reinterpret_cast<const float4*>(x0 - CHUNK + j0);
        const float4* p1 = reinterpret_cast<const float4*>(x1 - CHUNK + j0);
        const float sc = oma * A16K * 0.5f;   // tail pos = prev chunk, same offset
        #pragma unroll
        for (int q = 0; q < 4; ++q) {
            float4 a = p0[q], c = p1[q];
            b[q*4+0] -= sc * fmaf(a.x, a.x, c.x*c.x);
            b[q*4+1] -= sc * fmaf(a.y, a.y, c.y*c.y);
            b[q*4+2] -= sc * fmaf(a.z, a.z, c.z*c.z);
            b[q*4+3] -= sc * fmaf(a.w, a.w, c.w*c.w);
        }
    }

    // ---- 2. own-chunk thread scan ----
    float s = 0.0f;
    #pragma unroll
    for (int i = 0; i < EPT; ++i) s = fmaf(alpha, s, b[i]);

    // wave Hillis-Steele weighted inclusive scans (both phases share shuffles)
    float v = s, vp = s_prev, g = a16;
    #pragma unroll
    for (int off = 1; off < 64; off <<= 1) {
        float y  = __shfl_up(v,  off, 64);
        float yp = __shfl_up(vp, off, 64);
        if (lane >= off) { v = fmaf(g, y, v); vp = fmaf(g, yp, vp); }
        g *= g;
    }
    float Ew = __shfl_up(v, 1, 64);   // exclusive within-wave (own chunk)
    if (lane == 0) Ew = 0.0f;

    if (lane == 63) { wtotA[wid] = vp; wtotB[wid] = v; }
    __syncthreads();

    // carry = weighted total of prev chunk (Horner over wave totals)
    float carry = 0.0f;
    if (chunk > 0) {
        #pragma unroll
        for (int w = 0; w < NW; ++w) carry = fmaf(A1024, carry, wtotA[w]);
    }
    // exclusive prefix over preceding waves (own chunk)
    float wc = 0.0f;
    for (int w = 0; w < wid; ++w) wc = fmaf(A1024, wc, wtotB[w]);

    const float a16l = powiu(a16, (unsigned)lane);     // alpha^(16*lane)
    float pre_blk = fmaf(a16l, wc, Ew);                // block-local exclusive
    float e = fmaf(a16l * powiu(A1024, (unsigned)wid), carry, pre_blk);

    // ---- 3. element-wise env + gain + output ----
    #pragma unroll
    for (int q = 0; q < 4; ++q) {
        float4 oa, ob;
        float* poa = reinterpret_cast<float*>(&oa);
        float* pob = reinterpret_cast<float*>(&ob);
        const float* ia = reinterpret_cast<const float*>(&xa[q]);
        const float* ib = reinterpret_cast<const float*>(&xb[q]);
        #pragma unroll
        for (int k = 0; k < 4; ++k) {
            e = fmaf(alpha, e, b[q*4 + k]);
            float le = logf(e + 1e-5f);
            float xk = knee * (le - Tthr);
            float sp = fmaxf(xk, 0.0f) + log1pf(expf(-fabsf(xk)));
            float gain = expf(coef * sp);
            poa[k] = gain * ia[k];
            pob[k] = gain * ib[k];
        }
        reinterpret_cast<float4*>(out + base + j0)[q]        = oa;
        reinterpret_cast<float4*>(out + base + LLEN + j0)[q] = ob;
    }
}

extern "C" void kernel_launch(void* const* d_in, const int* in_sizes, int n_in,
                              void* d_out, int out_size, void* d_ws, size_t ws_size,
                              hipStream_t stream) {
    const float* x  = (const float*)d_in[0];
    const float* za = (const float*)d_in[1];
    const float* lt = (const float*)d_in[2];
    const float* lr = (const float*)d_in[3];
    const float* lk = (const float*)d_in[4];
    float* out = (float*)d_out;

    const int N = in_sizes[1];             // z_alpha is (N,1)
    dim3 grid(NBLK, N), block(TPB);
    k_fused<<<grid, block, 0, stream>>>(x, za, lt, lr, lk, out);
}

// Round 6
// 33.343 us; speedup vs baseline: 2.1806x; 1.0654x over previous
//
#include <hip/hip_runtime.h>
#include <cmath>

#define LLEN 131072
#define IIRL 16384
#define CHUNK 8192            // window (16384) spans exactly 2 prev chunks
#define NBLK (LLEN / CHUNK)   // 16 chunks per row
#define TPB 512
#define EPT (CHUNK / TPB)     // 16 elements per thread
#define NW (TPB / 64)         // 8 waves

__device__ __forceinline__ float powiu(float b, unsigned e) {
    float r = 1.0f;
    while (e) { if (e & 1u) r *= b; b *= b; e >>= 1; }
    return r;
}

__device__ __forceinline__ float sigmoidf(float z) {
    return 1.0f / (1.0f + expf(-z));
}

// ---------------------------------------------------------------------------
// Independent blocks, 2 resident/CU. CHUNK=8192, IIR window = 16384 => env in
// chunk c depends only on chunks {c, c-1, c-2}:
//   carry = env[start-1] = T1(c-1) + alpha^8192 * T2(c-2)
// where T(k) = zero-init weighted total of chunk k. Prev chunks need only a
// weighted reduction; own chunk does the full scan + gain + write.
// env[t] = a*env[t-1] + (1-a)*(ls[t] - a^16384*ls[t-16384]), ls = mean_c(x^2)
// ---------------------------------------------------------------------------
__global__ __launch_bounds__(TPB, 4) void k_fused(
    const float* __restrict__ x, const float* __restrict__ za,
    const float* __restrict__ lt, const float* __restrict__ lr,
    const float* __restrict__ lk, float* __restrict__ out)
{
    // XCD-aware swizzle: consecutive chunks of a row -> same XCD (L2 reuse of
    // the 2 prev-chunk re-reads). Dispatch id d round-robins XCDs (d % 8).
    const int d     = blockIdx.y * gridDim.x + blockIdx.x;
    const int total = gridDim.x * gridDim.y;       // 16*N, always % 8 == 0
    const int per   = total >> 3;
    const int w     = (d & 7) * per + (d >> 3);    // bijective
    const int chunk = w % NBLK, n = w / NBLK;

    const int tid = threadIdx.x, lane = tid & 63, wid = tid >> 6;

    const float alpha = sigmoidf(za[n]);
    const float omah  = 0.5f * (1.0f - alpha);
    const float A16K  = powiu(alpha, IIRL);   // ~always 0 in fp32
    const float Tthr  = lt[n] - 6.0f;
    const float ratio = 1.0f + expf(lr[n]);
    const float knee  = expf(lk[n] - 1.0f);
    const float coef  = (1.0f / ratio - 1.0f) / knee;

    const long  base = (long)n * 2 * LLEN + (long)chunk * CHUNK;
    const float* x0 = x + base;
    const float* x1 = x0 + LLEN;
    const int j0 = tid * EPT;

    const float a16   = powiu(alpha, 16u);    // per-thread segment weight
    const float A1024 = powiu(a16, 64u);      // per-wave segment weight

    // ---- own tile -> registers; b = 2*omah*ls (recurrence input) ----
    float4 xa[4], xb[4];
    float  b[EPT];
    {
        const float4* p0 = reinterpret_cast<const float4*>(x0 + j0);
        const float4* p1 = reinterpret_cast<const float4*>(x1 + j0);
        #pragma unroll
        for (int q = 0; q < 4; ++q) {
            xa[q] = p0[q]; xb[q] = p1[q];
            float4 a = xa[q], c = xb[q];
            b[q*4+0] = omah * fmaf(a.x, a.x, c.x*c.x);
            b[q*4+1] = omah * fmaf(a.y, a.y, c.y*c.y);
            b[q*4+2] = omah * fmaf(a.z, a.z, c.z*c.z);
            b[q*4+3] = omah * fmaf(a.w, a.w, c.w*c.w);
        }
    }

    // ---- prev-chunk weighted partial chains (zero init) ----
    float s1 = 0.0f, s2 = 0.0f;
    if (chunk > 0) {
        const float4* p0 = reinterpret_cast<const float4*>(x0 - CHUNK + j0);
        const float4* p1 = reinterpret_cast<const float4*>(x1 - CHUNK + j0);
        #pragma unroll
        for (int q = 0; q < 4; ++q) {
            float4 a = p0[q], c = p1[q];
            s1 = fmaf(alpha, s1, omah * fmaf(a.x, a.x, c.x*c.x));
            s1 = fmaf(alpha, s1, omah * fmaf(a.y, a.y, c.y*c.y));
            s1 = fmaf(alpha, s1, omah * fmaf(a.z, a.z, c.z*c.z));
            s1 = fmaf(alpha, s1, omah * fmaf(a.w, a.w, c.w*c.w));
        }
    }
    if (chunk > 1) {
        const float4* p0 = reinterpret_cast<const float4*>(x0 - 2*CHUNK + j0);
        const float4* p1 = reinterpret_cast<const float4*>(x1 - 2*CHUNK + j0);
        const float sc = A16K * omah;   // tail term lives in chunk c-2
        #pragma unroll
        for (int q = 0; q < 4; ++q) {
            float4 a = p0[q], c = p1[q];
            float l0 = fmaf(a.x, a.x, c.x*c.x);
            float l1 = fmaf(a.y, a.y, c.y*c.y);
            float l2 = fmaf(a.z, a.z, c.z*c.z);
            float l3 = fmaf(a.w, a.w, c.w*c.w);
            s2 = fmaf(alpha, s2, omah * l0);
            s2 = fmaf(alpha, s2, omah * l1);
            s2 = fmaf(alpha, s2, omah * l2);
            s2 = fmaf(alpha, s2, omah * l3);
            if (A16K != 0.0f) {
                b[q*4+0] -= sc * l0; b[q*4+1] -= sc * l1;
                b[q*4+2] -= sc * l2; b[q*4+3] -= sc * l3;
            }
        }
    }

    // ---- own-chunk thread scan ----
    float s = 0.0f;
    #pragma unroll
    for (int i = 0; i < EPT; ++i) s = fmaf(alpha, s, b[i]);

    // wave inclusive scan (own) — Hillis-Steele with weights
    float v = s, g = a16;
    #pragma unroll
    for (int off = 1; off < 64; off <<= 1) {
        float y = __shfl_up(v, off, 64);
        if (lane >= off) v = fmaf(g, y, v);
        g *= g;
    }
    float Ew = __shfl_up(v, 1, 64);
    if (lane == 0) Ew = 0.0f;

    // wave weighted totals (prev1, prev2): scale by a16^(63-lane), butterfly
    const float wscale = powiu(a16, (unsigned)(63 - lane));
    float t1 = s1 * wscale, t2 = s2 * wscale;
    #pragma unroll
    for (int off = 32; off; off >>= 1) {
        t1 += __shfl_xor(t1, off, 64);
        t2 += __shfl_xor(t2, off, 64);
    }

    __shared__ float wtB[NW], wtP1[NW], wtP2[NW];
    if (lane == 63) { wtB[wid] = v; wtP1[wid] = t1; wtP2[wid] = t2; }
    __syncthreads();

    // block totals of prev chunks (Horner over wave totals)
    float T1 = 0.0f, T2 = 0.0f;
    #pragma unroll
    for (int ww = 0; ww < NW; ++ww) {
        T1 = fmaf(A1024, T1, wtP1[ww]);
        T2 = fmaf(A1024, T2, wtP2[ww]);
    }
    const float A8192 = powiu(A1024, 8u);     // alpha^8192
    const float carry = fmaf(A8192, T2, T1);

    // exclusive prefix over preceding waves (own chunk)
    float wc = 0.0f;
    for (int ww = 0; ww < wid; ++ww) wc = fmaf(A1024, wc, wtB[ww]);

    const float a16l = powiu(a16, (unsigned)lane);
    float pre_blk = fmaf(a16l, wc, Ew);
    float e = fmaf(a16l * powiu(A1024, (unsigned)wid), carry, pre_blk);

    // ---- element-wise env + gain + output ----
    #pragma unroll
    for (int q = 0; q < 4; ++q) {
        float4 oa, ob;
        float* poa = reinterpret_cast<float*>(&oa);
        float* pob = reinterpret_cast<float*>(&ob);
        const float* ia = reinterpret_cast<const float*>(&xa[q]);
        const float* ib = reinterpret_cast<const float*>(&xb[q]);
        #pragma unroll
        for (int k = 0; k < 4; ++k) {
            e = fmaf(alpha, e, b[q*4 + k]);
            float le = logf(e + 1e-5f);
            float xk = knee * (le - Tthr);
            float sp = fmaxf(xk, 0.0f) + log1pf(expf(-fabsf(xk)));
            float gain = expf(coef * sp);
            poa[k] = gain * ia[k];
            pob[k] = gain * ib[k];
        }
        reinterpret_cast<float4*>(out + base + j0)[q]        = oa;
        reinterpret_cast<float4*>(out + base + LLEN + j0)[q] = ob;
    }
}

extern "C" void kernel_launch(void* const* d_in, const int* in_sizes, int n_in,
                              void* d_out, int out_size, void* d_ws, size_t ws_size,
                              hipStream_t stream) {
    const float* x  = (const float*)d_in[0];
    const float* za = (const float*)d_in[1];
    const float* lt = (const float*)d_in[2];
    const float* lr = (const float*)d_in[3];
    const float* lk = (const float*)d_in[4];
    float* out = (float*)d_out;

    const int N = in_sizes[1];             // z_alpha is (N,1)
    dim3 grid(NBLK, N), block(TPB);
    k_fused<<<grid, block, 0, stream>>>(x, za, lt, lr, lk, out);
}